// Round 14
// baseline (312.778 us; speedup 1.0000x reference)
//
#include <hip/hip_runtime.h>
#include <hip/hip_bf16.h>
#include <hip/hip_fp8.h>

typedef unsigned char u8;
typedef unsigned int u32;
typedef long long i64;
typedef __attribute__((ext_vector_type(4))) float f32x4;

#define NB 4096
#define ND 512          // bytes per fp8 row
#define NREPS (3*NB)
#define BM 128
#define BN 256
#define BK 64           // fp8 bytes per K-step -> NKT=8, buffers 24 KiB each
#define NKT (ND/BK)
#define ASZ (BM*BK)     // 8 KiB per buffer
#define BSZ (BN*BK)     // 16 KiB per buffer
#define NBLK ((NB/BM)*(NREPS/BN))   // 1536 blocks

// global -> LDS direct DMA, 16B/lane; LDS dest wave-uniform base + lane*16.
#define GLD16(gp, lp)                                                         \
  __builtin_amdgcn_global_load_lds(                                           \
      (const __attribute__((address_space(1))) void*)(gp),                    \
      (__attribute__((address_space(3))) void*)(lp), 16, 0, 0)

__device__ __forceinline__ u32 pk4(float a, float b, float c, float d) {
  __hip_fp8_e4m3 qa(a), qb(b), qc(c), qd(d);
  return (u32)qa.__x | ((u32)qb.__x << 8) | ((u32)qc.__x << 16) | ((u32)qd.__x << 24);
}

// Fused prep, no LDS/no barriers: waves 0..2 convert ts/i1/i2 row r -> fp8
// reps + fp32 norms (norms from ORIGINAL fp32); wave 3 re-reads i1/i2
// (L2-hot) for dist12 + minsq init. Block 0 zeroes out[0] and the
// done-counter for gemm's merged finalize (stream order protects both).
__global__ __launch_bounds__(256) void prep_all(
    const float* __restrict__ ts, const float* __restrict__ i1,
    const float* __restrict__ i2, u8* __restrict__ reps,
    float* __restrict__ norms, float* __restrict__ dist12,
    u32* __restrict__ minsq, float* __restrict__ out, u32* __restrict__ cnt)
{
  const int r = blockIdx.x;
  const int tid = threadIdx.x;
  const int wave = tid >> 6, lane = tid & 63;
  if (r == 0 && tid == 0) { out[0] = 0.f; cnt[0] = 0u; }

  if (wave < 3) {
    const float* src = (wave == 0) ? ts + (size_t)r * ND
                     : (wave == 1) ? i1 + (size_t)r * ND
                     :               i2 + (size_t)r * ND;
    const float4* s4 = (const float4*)src;
    float4 a = s4[lane*2+0];
    float4 b = s4[lane*2+1];
    float ss = a.x*a.x + a.y*a.y + a.z*a.z + a.w*a.w
             + b.x*b.x + b.y*b.y + b.z*b.z + b.w*b.w;
    uint2 pk;
    pk.x = pk4(a.x, a.y, a.z, a.w);
    pk.y = pk4(b.x, b.y, b.z, b.w);
    *(uint2*)(reps + (size_t)(wave*NB + r) * ND + lane*8) = pk;
    #pragma unroll
    for (int off = 32; off; off >>= 1) ss += __shfl_down(ss, off);
    if (lane == 0) norms[wave*NB + r] = ss;
  } else {
    const float4* a4 = (const float4*)(i1 + (size_t)r * ND);
    const float4* b4 = (const float4*)(i2 + (size_t)r * ND);
    float ss = 0.f;
    #pragma unroll
    for (int i = 0; i < 2; ++i) {
      float4 a = a4[lane*2+i], b = b4[lane*2+i];
      float d0 = a.x - b.x + 1e-6f, d1 = a.y - b.y + 1e-6f;
      float d2 = a.z - b.z + 1e-6f, d3 = a.w - b.w + 1e-6f;
      ss += d0*d0 + d1*d1 + d2*d2 + d3*d3;
    }
    #pragma unroll
    for (int off = 32; off; off >>= 1) ss += __shfl_down(ss, off);
    if (lane == 0) { dist12[r] = sqrtf(ss); minsq[r] = 0x7F800000u; }
  }
}

// fp8 16x16x32 operand read, BK=64 rows: lane (fr=row, fg) needs k-bytes
// s*32 + fg*8..+7 = granule q = 2s + (fg>>1) (0..3), byte (fg&1)*8.
// Physical slot = q ^ (row&3), matching the staging-side source swizzle.
__device__ __forceinline__ i64 rd8(const u8* __restrict__ S, int row,
                                   int s, int f) {
  const int q = (2*s + (f >> 1)) ^ (row & 3);
  return *(const i64*)&S[row*BK + q*16 + (f & 1)*8];
}

#define MFMA16(a,b,c) __builtin_amdgcn_mfma_f32_16x16x32_fp8_fp8((a),(b),(c),0,0,0)

// Fused distance-GEMM (fp8 e4m3) + per-row min + diagonal picks + ts@ts^T
// symmetry + MERGED FINALIZE (done-counter; one fewer graph node).
// 128x256 tile, BK=64 fp8, DOUBLE-BUFFERED at constant 48 KiB LDS
// (2 x (8+16) KiB): STAGE(next-buf) issues BEFORE frag reads + MFMA, so the
// per-step vmcnt(0) drain (inside the single __syncthreads) sits after
// ~800 cyc of compute -> load flight hidden. R6's dbuf failed via occupancy
// (64 KiB); here footprint is unchanged vs R13 -> clean schedule A/B.
// Grid dim3(32,48) M-fastest; ts tiles kept iff 2*ny <= mx; kept ts tiles
// fold the transpose into minsq[col] (min idempotent).
__global__ __launch_bounds__(512) void gemm_min(
    const u8* __restrict__ reps, const float* __restrict__ norms,
    u32* __restrict__ minsq, float* __restrict__ lpos1,
    float* __restrict__ lpos2, const float* __restrict__ dist12,
    float* __restrict__ out, u32* __restrict__ cnt)
{
  __shared__ u8 As[2*ASZ];
  __shared__ u8 Bs[2*BSZ];
  __shared__ float red[8];
  __shared__ u32 amLast;

  const int mx = blockIdx.x, ny = blockIdx.y;
  const int rowBase = mx * BM;     // ts rows
  const int colBase = ny * BN;     // reps rows (output cols)
  const bool tsTile = (colBase < NB);
  const bool skip = tsTile && (2*ny > mx);     // symmetric skip (uniform)
  const int tid  = threadIdx.x;

  if (!skip) {
    const int lane = tid & 63;
    const int wave = tid >> 6;          // 0..7
    const int wr = wave >> 2;           // 0..1 (M half)
    const int wc = wave & 3;            // 0..3 (N quarter)
    const int fr = lane & 15, fg = lane >> 4;

    // Staging: rows are 64 B (4 granules of 16 B); one GLD16 covers 16 rows
    // (64 lanes x 16B = 1 KiB). A = 8 chunks (1/wave), B = 16 (2/wave).
    const int rloc = lane >> 2;          // row within 16-row chunk
    const int sp   = lane & 3;           // physical granule slot
    const int g    = sp ^ (rloc & 3);    // swizzled source granule
    const u8* srcA  = reps + (size_t)(rowBase + wave*16      + rloc) * ND + g*16;
    const u8* srcB0 = reps + (size_t)(colBase + wave*32      + rloc) * ND + g*16;
    const u8* srcB1 = reps + (size_t)(colBase + wave*32 + 16 + rloc) * ND + g*16;
    u8* dstA  = &As[(wave*16)      * BK];
    u8* dstB0 = &Bs[(wave*32)      * BK];
    u8* dstB1 = &Bs[(wave*32 + 16) * BK];

#define STAGE(buf, koff)                                                      \
    { GLD16(srcA  + (koff), dstA  + (buf)*ASZ);                               \
      GLD16(srcB0 + (koff), dstB0 + (buf)*BSZ);                               \
      GLD16(srcB1 + (koff), dstB1 + (buf)*BSZ); }

    f32x4 acc[4][4];
    const f32x4 zero = {0.f, 0.f, 0.f, 0.f};
    #pragma unroll
    for (int i = 0; i < 4; ++i)
      #pragma unroll
      for (int j = 0; j < 4; ++j)
        acc[i][j] = zero;

    STAGE(0, 0);
    __syncthreads();
    for (int kt = 0; kt < NKT; ++kt) {
      const int cur = kt & 1;
      if (kt < NKT-1) STAGE(cur ^ 1, (kt+1)*BK);   // issue-early, other buffer
      const u8* Sa = As + cur*ASZ;
      const u8* Sb = Bs + cur*BSZ;
      i64 af[4][2], bfr[4][2];
      #pragma unroll
      for (int mf = 0; mf < 4; ++mf)
        #pragma unroll
        for (int s = 0; s < 2; ++s) {
          af[mf][s]  = rd8(Sa, wr*64 + mf*16 + fr, s, fg);
          bfr[mf][s] = rd8(Sb, wc*64 + mf*16 + fr, s, fg);
        }
      #pragma unroll
      for (int s = 0; s < 2; ++s)
        #pragma unroll
        for (int mf = 0; mf < 4; ++mf)
          #pragma unroll
          for (int nf = 0; nf < 4; ++nf)
            acc[mf][nf] = MFMA16(af[mf][s], bfr[nf][s], acc[mf][nf]);
      if (kt < NKT-1) __syncthreads();   // vmcnt(0): next tile landed (flight
    }                                    // overlapped reads+MFMA above)

    // Epilogue. C layout: col = fr, row = fg*4 + q within each 16x16 frag.
    float ncol[4];
    #pragma unroll
    for (int nf = 0; nf < 4; ++nf)
      ncol[nf] = norms[colBase + wc*64 + nf*16 + fr];
    const float INF = __builtin_inff();
    float cmin[4] = {INF, INF, INF, INF};

    #pragma unroll
    for (int mf = 0; mf < 4; ++mf) {
      #pragma unroll
      for (int q = 0; q < 4; ++q) {
        const int r_g = rowBase + wr*64 + mf*16 + fg*4 + q;
        const float ntr = norms[r_g];
        float vm = INF;
        #pragma unroll
        for (int nf = 0; nf < 4; ++nf) {
          const int c_g = colBase + wc*64 + nf*16 + fr;
          const float dot = acc[mf][nf][q];
          const float sq = ntr + ncol[nf] - 2.0f * dot;
          if (c_g == r_g + NB)   lpos1[r_g] = sq;   // unique writer
          if (c_g == r_g + 2*NB) lpos2[r_g] = sq;   // unique writer
          const bool excl = (c_g == r_g) || (c_g == r_g + NB) || (c_g == r_g + 2*NB);
          const float v = excl ? INF : fmaxf(sq, 0.0f);
          vm = fminf(vm, v);
          cmin[nf] = fminf(cmin[nf], v);
        }
        #pragma unroll
        for (int off = 1; off < 16; off <<= 1)
          vm = fminf(vm, __shfl_xor(vm, off));
        if (fr == 0)
          atomicMin(minsq + r_g, __float_as_uint(vm));  // nonneg floats as uints
      }
    }

    if (tsTile) {
      #pragma unroll
      for (int nf = 0; nf < 4; ++nf) {
        float cm = cmin[nf];
        cm = fminf(cm, __shfl_xor(cm, 16));
        cm = fminf(cm, __shfl_xor(cm, 32));
        if (fg == 0) {
          const int c_g = colBase + wc*64 + nf*16 + fr;
          atomicMin(minsq + c_g, __float_as_uint(cm));
        }
      }
    }
    __threadfence();   // make lpos/minsq writes device-visible before count
  }

  // Merged finalize: every block (incl. skipped) increments; last block
  // (all 1536 increments seen -> all writes fenced) reduces the loss.
  if (tid == 0) amLast = (atomicAdd(cnt, 1u) == NBLK - 1u) ? 1u : 0u;
  __syncthreads();
  if (amLast) {
    __threadfence();
    float s = 0.f;
    for (int r = tid; r < NB; r += 512) {
      float l1 = sqrtf(fmaxf(lpos1[r], 0.f));
      float l2 = sqrtf(fmaxf(lpos2[r], 0.f));
      float neg = sqrtf(__uint_as_float(minsq[r]));   // already clamped >= 0
      float pos = l1 + l2 + dist12[r];
      s += fmaxf(pos - neg + 0.1f, 0.f) + fmaxf(l1, l2);
    }
    #pragma unroll
    for (int off = 32; off; off >>= 1) s += __shfl_down(s, off);
    if ((tid & 63) == 0) red[tid >> 6] = s;
    __syncthreads();
    if (tid == 0) {
      float t = 0.f;
      #pragma unroll
      for (int i = 0; i < 8; ++i) t += red[i];
      out[0] = t * (1.0f / NB);
    }
  }
}

extern "C" void kernel_launch(void* const* d_in, const int* in_sizes, int n_in,
                              void* d_out, int out_size, void* d_ws, size_t ws_size,
                              hipStream_t stream) {
  const float* ts = (const float*)d_in[0];
  const float* i1 = (const float*)d_in[1];
  const float* i2 = (const float*)d_in[2];
  float* out = (float*)d_out;

  char* p = (char*)d_ws;
  u8* reps     = (u8*)p;             p += (size_t)NREPS * ND * sizeof(u8);   // 6.3 MB
  float* norms = (float*)p;          p += (size_t)NREPS * sizeof(float);
  float* dist12 = (float*)p;         p += (size_t)NB * sizeof(float);
  u32* minsq   = (u32*)p;            p += (size_t)NB * sizeof(u32);
  float* lpos1 = (float*)p;          p += (size_t)NB * sizeof(float);
  float* lpos2 = (float*)p;          p += (size_t)NB * sizeof(float);
  u32* cnt     = (u32*)p;            p += sizeof(u32);

  prep_all<<<NB, 256, 0, stream>>>(ts, i1, i2, reps, norms, dist12, minsq, out, cnt);
  dim3 grid(NB / BM, NREPS / BN);   // 32 x 48, M-fastest (L2 locality)
  gemm_min<<<grid, 512, 0, stream>>>(reps, norms, minsq, lpos1, lpos2,
                                     dist12, out, cnt);
}